// Round 9
// baseline (1633.074 us; speedup 1.0000x reference)
//
#include <hip/hip_runtime.h>
#include <hip/hip_cooperative_groups.h>
#include <math.h>

namespace cg = cooperative_groups;

typedef unsigned long long u64;
typedef unsigned int u32;

#define HH 160
#define WW 160
#define CC 256
#define NPX 25600
#define NA 9
#define NSC 230400
#define K_SEL 6000
#define SEL_PAD 6016
#define IMS 2560.0f
#define DWH 4.135166556742356f

struct SelState { u64 prefix; u32 r; u32 cnt; };

// ---- ws layout (bytes) ----
#define OFF_BOXES   0u               // float4[230400] -> 3,686,400
#define OFF_SCORES  3686400u         // float [230400]
#define OFF_KEYS    4608000u         // u64   [230400]
#define OFF_STATE   7499776u
#define OFF_SELK    7500032u         // u64[6016]
#define OFF_SX1     7548160u
#define OFF_SY1     7572224u
#define OFF_SX2     7596288u
#define OFF_SY2     7620352u
#define OFF_SSC     7644416u
#define OFF_ALIVE   7668480u
#define OFF_MASKT   11503104u        // u64[94*6016 + 128 pad] -> ends 16,028,160
#define OFF_WT      16028160u        // float[2304*256] -> ends 18,387,456
#define OFF_HIST    18387456u        // u32[2*8192] -> ends 18,452,992
#define OFF_RPN     27869184u        // float[256*160*160] -> ends 54,083,584

__constant__ float c_bx1[9] = {-91.f,-181.f,-362.f,-64.f,-128.f,-256.f,-45.f,-91.f,-181.f};
__constant__ float c_by1[9] = {-45.f,-91.f,-181.f,-64.f,-128.f,-256.f,-91.f,-181.f,-362.f};
__constant__ float c_bx2[9] = { 91.f, 181.f, 362.f, 64.f, 128.f, 256.f, 45.f, 91.f, 181.f};
__constant__ float c_by2[9] = { 45.f,  91.f, 181.f, 64.f, 128.f, 256.f, 91.f, 181.f, 362.f};

__device__ inline u64 shfl64(u64 v, int src) {
  int lo = (int)(v & 0xFFFFFFFFull), hi = (int)(v >> 32);
  lo = __shfl(lo, src, 64); hi = __shfl(hi, src, 64);
  return ((u64)(u32)hi << 32) | (u32)lo;
}

// ---------------- 0. weight transpose: w[oc][ic*9+tap] -> wT[ic*9+tap][oc] ----------------
__global__ __launch_bounds__(256) void wtr_k(const float* __restrict__ w, float* __restrict__ wT) {
  __shared__ float t[64][65];
  int kb = blockIdx.x % 36;
  int ob = blockIdx.x / 36;
  int tid = threadIdx.x;
  for (int it = 0; it < 16; it++) {
    int idx = it * 256 + tid;
    int row = idx >> 6, colk = idx & 63;
    t[row][colk] = w[(size_t)(ob * 64 + row) * 2304 + kb * 64 + colk];
  }
  __syncthreads();
  for (int it = 0; it < 16; it++) {
    int idx = it * 256 + tid;
    int krow = idx >> 6, occ = idx & 63;
    wT[(size_t)(kb * 64 + krow) * 256 + ob * 64 + occ] = t[occ][krow];
  }
}

// ---------------- 1. conv3x3 + bias + relu (R1 scalar-weight, validated local optimum) ----------------
// 7-round conv ledger: R1 scalar-weight = 510us/55% (best); all-LDS 573;
// 8x8 regtile 618 (write conflicts); 1-wave 1055 (spill); 8x4 617; LDS-
// broadcast weights 594/52%. Conv is frozen; the optimization frontier is
// the ~918us non-conv tail (launch overhead + serial kernels).
__global__ __launch_bounds__(256) void conv_k(const float* __restrict__ feat,
                                              const float* __restrict__ wT,
                                              const float* __restrict__ bias,
                                              float* __restrict__ outp) {
  int bx = blockIdx.x;              // 800 = 5 * 40 * 4
  int ct = bx % 5;
  int rt = (bx / 5) % 40;
  int ot = bx / 200;
  int x0 = ct * 32, y0 = rt * 4, oc0 = ot * 64;

  __shared__ float ps[2][8][6][36];

  int tid = threadIdx.x;
  int lane = tid & 63;
  int wvu = __builtin_amdgcn_readfirstlane(tid >> 6);   // wave id, SGPR-uniform
  int col = lane & 31;
  int s = lane >> 5;
  int ocw = oc0 + wvu * 16;

  // precompute staging map (constant over chunks): it 0..5 all threads, it 6 tid<96
  int s_off[7]; int s_lof[7]; bool s_val[7];
#pragma unroll
  for (int it = 0; it < 7; it++) {
    int idx = tid + it * 256;
    bool ex = (idx < 1632);
    int icl = idx / 204, rem = idx % 204;
    int r = rem / 34, c = rem % 34;
    int gy = y0 + r - 1, gx = x0 + c - 1;
    s_val[it] = ex && ((unsigned)gy < 160u) && ((unsigned)gx < 160u);
    s_off[it] = icl * NPX + gy * WW + gx;
    s_lof[it] = ex ? ((icl * 6 + r) * 36 + c) : 0;
    if (!ex) s_lof[it] = -1;
  }

  float acc0[16], acc1[16];
#pragma unroll
  for (int i = 0; i < 16; i++) { acc0[i] = 0.f; acc1[i] = 0.f; }

  float st[7];
  // stage chunk 0 into ps[0]
#pragma unroll
  for (int it = 0; it < 7; it++) {
    float v = 0.f;
    if (s_val[it]) v = feat[s_off[it]];
    if (s_lof[it] >= 0) (&ps[0][0][0][0])[s_lof[it]] = v;
  }
  __syncthreads();

  for (int c8 = 0; c8 < 32; c8++) {
    // issue global loads for next chunk (overlap with compute below)
    if (c8 < 31) {
      int icn = (c8 + 1) * 8;
#pragma unroll
      for (int it = 0; it < 7; it++) {
        st[it] = 0.f;
        if (s_val[it]) st[it] = feat[icn * NPX + s_off[it]];
      }
    }
    int buf = c8 & 1;
    int ic0 = c8 * 8;
    for (int icl = 0; icl < 8; icl++) {       // not unrolled: I-cache
      float p[4][3];
#pragma unroll
      for (int rr = 0; rr < 4; rr++)
#pragma unroll
        for (int cc = 0; cc < 3; cc++)
          p[rr][cc] = ps[buf][icl][2 * s + rr][col + cc];
      const float* wb = wT + (size_t)(ic0 + icl) * 9 * 256 + ocw;   // uniform addr
#pragma unroll
      for (int dy = 0; dy < 3; dy++) {
#pragma unroll
        for (int dx = 0; dx < 3; dx++) {
          const float* wr = wb + (dy * 3 + dx) * 256;
#pragma unroll
          for (int i = 0; i < 16; i++) {
            float wv_ = wr[i];                // s_load -> SGPR operand
            acc0[i] += wv_ * p[dy][dx];
            acc1[i] += wv_ * p[dy + 1][dx];
          }
        }
      }
    }
    if (c8 < 31) {
      __syncthreads();                        // everyone done reading ps[buf^1]
      float* dst = &ps[buf ^ 1][0][0][0];
#pragma unroll
      for (int it = 0; it < 7; it++)
        if (s_lof[it] >= 0) dst[s_lof[it]] = st[it];
      __syncthreads();                        // writes visible
    }
  }
#pragma unroll
  for (int i = 0; i < 16; i++) {
    int oc = ocw + i;
    float bv = bias[oc];
    size_t base = (size_t)oc * NPX + (y0 + 2 * s) * WW + x0 + col;
    outp[base] = fmaxf(acc0[i] + bv, 0.f);
    outp[base + WW] = fmaxf(acc1[i] + bv, 0.f);
  }
}

// ---------------- 2. heads + sigmoid + decode + clip + key ----------------
__global__ __launch_bounds__(256) void heads_k(const float* __restrict__ rpn,
                                               const float* __restrict__ cls_w,
                                               const float* __restrict__ cls_b,
                                               const float* __restrict__ bbox_w,
                                               const float* __restrict__ bbox_b,
                                               float4* __restrict__ boxes,
                                               float* __restrict__ scores,
                                               u64* __restrict__ keys) {
  __shared__ float sf[32][260];
  __shared__ float so[45][33];
  int tid = threadIdx.x;
  int px0 = blockIdx.x * 32;
  for (int idx = tid; idx < 8192; idx += 256) {
    int c = idx >> 5, p = idx & 31;
    sf[p][c] = rpn[(size_t)c * NPX + px0 + p];
  }
  __syncthreads();
  int p = tid & 31, g = tid >> 5;
  for (int oi = 0; oi < 6; oi++) {
    int o = g + oi * 8;
    if (o >= 45) break;
    const float* wr = (o < 9) ? (cls_w + o * CC) : (bbox_w + (o - 9) * CC);
    float bsum = (o < 9) ? cls_b[o] : bbox_b[o - 9];
    float s = 0.f;
    for (int c = 0; c < CC; c += 4) {
      float4 f = *(const float4*)&sf[p][c];
      float4 wv = *(const float4*)&wr[c];
      s += f.x * wv.x; s += f.y * wv.y; s += f.z * wv.z; s += f.w * wv.w;
    }
    so[o][p] = s + bsum;
  }
  __syncthreads();
  for (int t = tid; t < 288; t += 256) {
    int a = t >> 5, pp = t & 31;
    int px = px0 + pp;
    int y = px / 160, x = px - y * 160;
    float logit = so[a][pp];
    float sc = 1.f / (1.f + expf(-logit));
    float ddx = so[9 + 4 * a][pp], ddy = so[10 + 4 * a][pp];
    float ddw = fminf(so[11 + 4 * a][pp], DWH);
    float ddh = fminf(so[12 + 4 * a][pp], DWH);
    float ax1 = x * 16.f + c_bx1[a];
    float ay1 = y * 16.f + c_by1[a];
    float ax2 = x * 16.f + c_bx2[a];
    float ay2 = y * 16.f + c_by2[a];
    float aw = ax2 - ax1, ah = ay2 - ay1;
    float cx = ax1 + 0.5f * aw, cy = ay1 + 0.5f * ah;
    float pcx = ddx * aw + cx, pcy = ddy * ah + cy;
    float pw = expf(ddw) * aw, phh = expf(ddh) * ah;
    float x1 = pcx - 0.5f * pw, y1 = pcy - 0.5f * phh;
    float x2 = pcx + 0.5f * pw, y2 = pcy + 0.5f * phh;
    x1 = fminf(fmaxf(x1, 0.f), IMS); x2 = fminf(fmaxf(x2, 0.f), IMS);
    y1 = fminf(fmaxf(y1, 0.f), IMS); y2 = fminf(fmaxf(y2, 0.f), IMS);
    int gidx = px * 9 + a;
    boxes[gidx] = make_float4(x1, y1, x2, y2);
    scores[gidx] = sc;
    u32 sb = __float_as_uint(sc);
    u32 mono = (sb & 0x80000000u) ? ~sb : (sb | 0x80000000u);
    keys[gidx] = ((u64)mono << 32) | (u64)(0xFFFFFFFFu - (u32)gidx);
  }
}

// ---------------- 3. ONE-LAUNCH cooperative radix select + compact ----------------
// R8 had 12 launches (zero + 5x hist + 5x scan + compact); tail accounting
// says per-launch overhead x 19 launches is the likely whale (~700us of the
// 918us tail is unexplained by kernel-time estimates). This kernel fuses the
// entire selection into ONE cooperative launch with grid.sync() phase
// boundaries. Improvements folded in:
//  - per-block LDS histograms (8192 bins, 32KB) flushed as <=1 global atomic
//    per nonzero bin per block: hottest-bin contention 3600 wave-atomics ->
//    256 block-atomics;
//  - keys stay L2-resident across all 5 passes;
//  - double-buffered global hist: blocks 1..255 zero the next buffer while
//    block 0 scans the current one.
// Semantics identical to R8: widths (13,13,13,13,12), same suffix-walk, same
// full-64-bit threshold compact -> same exact selk set -> absmax 0.0.
__global__ __launch_bounds__(1024) void selco_k(const u64* __restrict__ keys,
                                                SelState* st,
                                                u32* __restrict__ ghist,   // u32[2][8192]
                                                u64* __restrict__ selk) {
  cg::grid_group grid = cg::this_grid();
  __shared__ u32 lh[8192];
  __shared__ u32 tsum[1024];
  __shared__ u32 wsum[16];
  int tid = threadIdx.x;
  int gid = blockIdx.x * 1024 + tid;       // grid 256 x 1024 = 262144 >= NSC
  int lane = tid & 63, wv = tid >> 6;
  const int widths[5] = {13, 13, 13, 13, 12};

  // prologue: zero both global hist buffers, init state
  if (gid < 8192) { ghist[gid] = 0; ghist[8192 + gid] = 0; }
  if (gid == 0) { st->prefix = 0; st->r = K_SEL; st->cnt = 0; }
  grid.sync();

  bool have = (gid < NSC);
  u64 k = have ? keys[gid] : 0ull;

  int bitsdone = 0;
  for (int pass = 0; pass < 5; pass++) {
    int wbits = widths[pass];
    int nbins = 1 << wbits;
    int shift = 64 - bitsdone - wbits;
    u32* gh = ghist + (pass & 1) * 8192;

    // zero LDS hist
    for (int i = tid; i < nbins; i += 1024) lh[i] = 0;
    __syncthreads();
    // local histogram
    bool active = have;
    if (active && bitsdone > 0)
      active = ((k >> (64 - bitsdone)) == ((volatile SelState*)st)->prefix);
    if (active) {
      u32 digit = (u32)((k >> shift) & (u64)(nbins - 1));
      atomicAdd(&lh[digit], 1u);
    }
    __syncthreads();
    // flush nonzero bins to global
    for (int i = tid; i < nbins; i += 1024) {
      u32 v = lh[i];
      if (v) atomicAdd(&gh[i], v);
    }
    grid.sync();

    if (blockIdx.x == 0) {
      // scan: pick the bin containing rank r (identical walk to R8 scan_k)
      int bpt = nbins >> 10;
      u32 r = st->r;
      u32 s = 0;
      for (int b = 0; b < bpt; b++) s += gh[tid * bpt + b];
      tsum[tid] = s;
      u32 v = s;
#pragma unroll
      for (int off = 1; off < 64; off <<= 1) v += (u32)__shfl_xor((int)v, off, 64);
      if (lane == 0) wsum[wv] = v;
      __syncthreads();
      if (tid == 0) {
        u32 cum = 0;
        int ws = 15;
        while (ws > 0 && cum + wsum[ws] < r) { cum += wsum[ws]; ws--; }
        int t = ws * 64 + 63, tend = ws * 64;
        while (t > tend && cum + tsum[t] < r) { cum += tsum[t]; t--; }
        int b = t * bpt + bpt - 1, bend = t * bpt;
        while (b > bend && cum + gh[b] < r) { cum += gh[b]; b--; }
        st->prefix = (st->prefix << wbits) | (u64)(u32)b;
        st->r = r - cum;
        __threadfence();
      }
    } else {
      // zero the buffer pass p+1 will use (scan of pass p-1 is done with it)
      u32* go = ghist + ((pass & 1) ^ 1) * 8192;
      int i = (blockIdx.x - 1) * 1024 + tid;
      if (i < 8192) go[i] = 0;
    }
    grid.sync();
    bitsdone += wbits;
  }

  // compact: exact 64-bit threshold (identical to R8 compact_k)
  u64 thr = ((volatile SelState*)st)->prefix;
  if (have && k >= thr) {
    u32 pos = atomicAdd(&st->cnt, 1u);
    selk[pos] = k;
  }
}

// ---------------- 4. exact rank -> sorted SoA ----------------
__global__ __launch_bounds__(64) void rank_k(const u64* __restrict__ selk,
                                             const float4* __restrict__ boxes,
                                             const float* __restrict__ scores,
                                             float* sx1, float* sy1, float* sx2, float* sy2, float* ssc) {
  __shared__ __align__(16) u64 sk[SEL_PAD];
  int lane = threadIdx.x;
  for (int i = lane; i < SEL_PAD; i += 64) sk[i] = (i < K_SEL) ? selk[i] : 0ull;
  __syncthreads();
  int n = blockIdx.x * 64 + lane;
  u64 myk = (n < K_SEL) ? selk[n] : ~0ull;
  int cnt = 0;
  const ulonglong2* sk2 = (const ulonglong2*)sk;
#pragma unroll 8
  for (int j = 0; j < SEL_PAD / 2; j++) {
    ulonglong2 kk = sk2[j];
    cnt += (kk.x > myk) ? 1 : 0;
    cnt += (kk.y > myk) ? 1 : 0;
  }
  if (n < K_SEL) {
    u32 oidx = 0xFFFFFFFFu - (u32)(myk & 0xFFFFFFFFull);
    float4 b = boxes[oidx];
    sx1[cnt] = b.x; sy1[cnt] = b.y; sx2[cnt] = b.z; sy2[cnt] = b.w;
    ssc[cnt] = scores[oidx];
  }
}

// ---------------- 5. pairwise suppression mask (column-major) ----------------
__global__ __launch_bounds__(256) void mask_k(const float* __restrict__ sx1, const float* __restrict__ sy1,
                                              const float* __restrict__ sx2, const float* __restrict__ sy2,
                                              u64* __restrict__ maskT) {
  __shared__ float jb[5][3008];
  int tid = threadIdx.x;
  int wv = tid >> 6, lane = tid & 63;
  int ibase = blockIdx.x * 32 + wv * 8;
  float ix1[8], iy1[8], ix2[8], iy2[8], ia[8];
#pragma unroll
  for (int r = 0; r < 8; r++) {
    int i = ibase + r;
    ix1[r] = sx1[i]; iy1[r] = sy1[i]; ix2[r] = sx2[i]; iy2[r] = sy2[i];
    ia[r] = (ix2[r] - ix1[r]) * (iy2[r] - iy1[r]);
  }
  for (int half = 0; half < 2; half++) {
    int j0 = half * 3008;
    __syncthreads();
    for (int idx = tid; idx < 3008; idx += 256) {
      int j = j0 + idx;
      bool v = j < K_SEL;
      float a = v ? sx1[j] : 0.f;
      float b = v ? sy1[j] : 0.f;
      float c = v ? sx2[j] : 0.f;
      float d = v ? sy2[j] : 0.f;
      jb[0][idx] = a; jb[1][idx] = b; jb[2][idx] = c; jb[3][idx] = d;
      jb[4][idx] = (c - a) * (d - b);
    }
    __syncthreads();
    for (int wi = 0; wi < 47; wi++) {
      int w = half * 47 + wi;
      int jl = wi * 64 + lane;
      int j = j0 + jl;
      float jx1 = jb[0][jl], jy1 = jb[1][jl], jx2 = jb[2][jl], jy2 = jb[3][jl], ja = jb[4][jl];
      bool jv = j < K_SEL;
#pragma unroll
      for (int r = 0; r < 8; r++) {
        int i = ibase + r;
        float xl = fmaxf(ix1[r], jx1), yt = fmaxf(iy1[r], jy1);
        float xr = fminf(ix2[r], jx2), yb = fminf(iy2[r], jy2);
        float iw = fmaxf(xr - xl, 0.f), ihh = fmaxf(yb - yt, 0.f);
        float inter = iw * ihh;
        bool sup = jv && (j > i) && (inter > 0.7f * (ia[r] + ja - inter));
        u64 bits = __ballot(sup);
        if (lane == 0 && i < K_SEL) maskT[(size_t)w * SEL_PAD + i] = bits;
      }
    }
  }
}

// ---------------- 6. greedy NMS: multi-wave column pull (1 block x 16 waves) ----------------
__global__ __launch_bounds__(1024) void nms_k(const u64* __restrict__ maskT,
                                              const float* __restrict__ sx1, const float* __restrict__ sy1,
                                              const float* __restrict__ sx2, const float* __restrict__ sy2,
                                              u64* __restrict__ alive_out) {
  __shared__ u64 sdiag[94 * 64];
  __shared__ u64 skept[96];
  __shared__ u64 svalid[94];
  __shared__ u64 wacc[16];
  int tid = threadIdx.x;
  int wv = tid >> 6, lane = tid & 63;

  if (tid < 96) skept[tid] = 0ull;
  for (int w = wv; w < 94; w += 16) {
    int p = w * 64 + lane;
    float bw = sx2[p] - sx1[p], bh = sy2[p] - sy1[p];
    bool ok = (p < K_SEL) && (bw >= 16.f) && (bh >= 16.f);
    u64 bits = __ballot(ok);
    if (lane == 0) svalid[w] = bits;
  }
  for (int idx = tid; idx < 94 * 64; idx += 1024) {
    int cc = idx >> 6;
    sdiag[idx] = maskT[(size_t)cc * SEL_PAD + cc * 64 + (idx & 63)];
  }
  __syncthreads();

  for (int c = 0; c < 94; c++) {
    size_t colbase = (size_t)c * SEL_PAD;
    int i0 = 2 * tid;
    ulonglong2 v0 = *(const ulonglong2*)&maskT[colbase + i0];
    ulonglong2 v1 = *(const ulonglong2*)&maskT[colbase + i0 + 2048];
    ulonglong2 v2 = *(const ulonglong2*)&maskT[colbase + i0 + 4096];
    u64 k0 = skept[i0 >> 6];
    u64 k1 = skept[(i0 + 2048) >> 6];
    u64 k2 = skept[(i0 + 4096) >> 6];
    int sh = i0 & 63;
    u64 acc = 0;
    if ((k0 >> sh) & 1) acc |= v0.x;
    if ((k0 >> (sh + 1)) & 1) acc |= v0.y;
    if ((k1 >> sh) & 1) acc |= v1.x;
    if ((k1 >> (sh + 1)) & 1) acc |= v1.y;
    if ((k2 >> sh) & 1) acc |= v2.x;
    if ((k2 >> (sh + 1)) & 1) acc |= v2.y;
    u32 lo = (u32)acc, hi = (u32)(acc >> 32);
#pragma unroll
    for (int off = 1; off < 64; off <<= 1) {
      lo |= (u32)__shfl_xor((int)lo, off, 64);
      hi |= (u32)__shfl_xor((int)hi, off, 64);
    }
    if (lane == 0) wacc[wv] = ((u64)hi << 32) | (u64)lo;
    __syncthreads();
    if (wv == 0) {
      u64 a = wacc[lane & 15];
      u32 alo = (u32)a, ahi = (u32)(a >> 32);
#pragma unroll
      for (int off = 1; off < 16; off <<= 1) {
        alo |= (u32)__shfl_xor((int)alo, off, 64);
        ahi |= (u32)__shfl_xor((int)ahi, off, 64);
      }
      u64 supp = ((u64)ahi << 32) | (u64)alo;
      u64 cur = svalid[c] & ~supp;
      u64 d = sdiag[c * 64 + lane];
      u64 rem = cur, kept = 0;
      while (rem) {
        int b = __builtin_ctzll(rem);
        kept |= (1ull << b);
        u64 dead = shfl64(d, b);
        rem &= ~dead;
        rem &= ~(1ull << b);
      }
      if (lane == 0) skept[c] = kept;
    }
    __syncthreads();
  }
  if (tid < 94) alive_out[tid] = skept[tid];
}

// ---------------- 7. finalize ----------------
__global__ __launch_bounds__(128) void final_k(const u64* __restrict__ alive,
                                               const float* __restrict__ sx1, const float* __restrict__ sy1,
                                               const float* __restrict__ sx2, const float* __restrict__ sy2,
                                               const float* __restrict__ ssc, float* __restrict__ out) {
  __shared__ u64 aw[94];
  __shared__ u32 pre[95];
  int tid = threadIdx.x;
  if (tid < 94) aw[tid] = alive[tid];
  __syncthreads();
  if (tid == 0) {
    u32 s = 0;
    for (int w = 0; w < 94; w++) { pre[w] = s; s += (u32)__popcll(aw[w]); }
    pre[94] = s;
  }
  __syncthreads();
  u32 total = pre[94];
  for (int p = tid; p < K_SEL; p += 128) {
    int w = p >> 6, b = p & 63;
    u64 word = aw[w];
    u32 kb = pre[w] + (u32)__popcll(word & ((1ull << b) - 1ull));
    bool kept = (word >> b) & 1ull;
    int slot = -1; float sc = -1.f;
    if (kept) {
      if (kb < 300) { slot = (int)kb; sc = ssc[p]; }
    } else {
      u32 s2 = total + (u32)p - kb;
      if (s2 < 300) slot = (int)s2;
    }
    if (slot >= 0) {
      out[slot * 5 + 0] = sx1[p];
      out[slot * 5 + 1] = sy1[p];
      out[slot * 5 + 2] = sx2[p];
      out[slot * 5 + 3] = sy2[p];
      out[slot * 5 + 4] = sc;
    }
  }
}

extern "C" void kernel_launch(void* const* d_in, const int* in_sizes, int n_in,
                              void* d_out, int out_size, void* d_ws, size_t ws_size,
                              hipStream_t stream) {
  const float* feat   = (const float*)d_in[0];
  const float* conv_w = (const float*)d_in[2];
  const float* conv_b = (const float*)d_in[3];
  const float* cls_w  = (const float*)d_in[4];
  const float* cls_b  = (const float*)d_in[5];
  const float* bbox_w = (const float*)d_in[6];
  const float* bbox_b = (const float*)d_in[7];
  float* out = (float*)d_out;
  char* ws = (char*)d_ws;

  float*  rpn    = (float*)(ws + OFF_RPN);
  float4* boxes  = (float4*)(ws + OFF_BOXES);
  float*  scores = (float*)(ws + OFF_SCORES);
  u64*    keys   = (u64*)(ws + OFF_KEYS);
  SelState* st   = (SelState*)(ws + OFF_STATE);
  u64*    selk   = (u64*)(ws + OFF_SELK);
  float*  sx1    = (float*)(ws + OFF_SX1);
  float*  sy1    = (float*)(ws + OFF_SY1);
  float*  sx2    = (float*)(ws + OFF_SX2);
  float*  sy2    = (float*)(ws + OFF_SY2);
  float*  ssc    = (float*)(ws + OFF_SSC);
  u64*    alive  = (u64*)(ws + OFF_ALIVE);
  u64*    maskT  = (u64*)(ws + OFF_MASKT);
  float*  wT     = (float*)(ws + OFF_WT);
  u32*    hist   = (u32*)(ws + OFF_HIST);

  wtr_k<<<144, 256, 0, stream>>>(conv_w, wT);
  conv_k<<<800, 256, 0, stream>>>(feat, wT, conv_b, rpn);
  heads_k<<<800, 256, 0, stream>>>(rpn, cls_w, cls_b, bbox_w, bbox_b, boxes, scores, keys);

  {
    void* args[] = {(void*)&keys, (void*)&st, (void*)&hist, (void*)&selk};
    hipLaunchCooperativeKernel((const void*)selco_k, dim3(256), dim3(1024),
                               args, 0, stream);
  }

  rank_k<<<94, 64, 0, stream>>>(selk, boxes, scores, sx1, sy1, sx2, sy2, ssc);
  mask_k<<<188, 256, 0, stream>>>(sx1, sy1, sx2, sy2, maskT);
  nms_k<<<1, 1024, 0, stream>>>(maskT, sx1, sy1, sx2, sy2, alive);
  final_k<<<1, 128, 0, stream>>>(alive, sx1, sy1, sx2, sy2, ssc, out);
}

// Round 10
// 1532.886 us; speedup vs baseline: 1.0654x; 1.0654x over previous
//
#include <hip/hip_runtime.h>
#include <math.h>

typedef unsigned long long u64;
typedef unsigned int u32;

#define HH 160
#define WW 160
#define CC 256
#define NPX 25600
#define NA 9
#define NSC 230400
#define K_SEL 6000
#define SEL_PAD 6016
#define IMS 2560.0f
#define DWH 4.135166556742356f

struct SelState { u64 prefix; u32 r; u32 cnt; };

// ---- ws layout (bytes) ----
#define OFF_BOXES   0u               // float4[230400] -> 3,686,400
#define OFF_SCORES  3686400u         // float [230400]
#define OFF_KEYS    4608000u         // u64   [230400]
#define OFF_STATE   7499776u
#define OFF_SELK    7500032u         // u64[6016]
#define OFF_SX1     7548160u
#define OFF_SY1     7572224u
#define OFF_SX2     7596288u
#define OFF_SY2     7620352u
#define OFF_SSC     7644416u
#define OFF_ALIVE   7668480u
#define OFF_MASKT   11503104u        // u64[94*6016 + 128 pad] -> ends 16,028,160
#define OFF_WT      16028160u        // float[2304*256] -> ends 18,387,456
#define OFF_HIST    18387456u        // u32[5*8192] -> ends 18,551,296
#define OFF_DONE    18551296u        // u32[8] -> ends 18,551,328
#define OFF_RPN     27869184u        // float[256*160*160] -> ends 54,083,584

__constant__ float c_bx1[9] = {-91.f,-181.f,-362.f,-64.f,-128.f,-256.f,-45.f,-91.f,-181.f};
__constant__ float c_by1[9] = {-45.f,-91.f,-181.f,-64.f,-128.f,-256.f,-91.f,-181.f,-362.f};
__constant__ float c_bx2[9] = { 91.f, 181.f, 362.f, 64.f, 128.f, 256.f, 45.f, 91.f, 181.f};
__constant__ float c_by2[9] = { 45.f,  91.f, 181.f, 64.f, 128.f, 256.f, 91.f, 181.f, 362.f};

__device__ inline u64 shfl64(u64 v, int src) {
  int lo = (int)(v & 0xFFFFFFFFull), hi = (int)(v >> 32);
  lo = __shfl(lo, src, 64); hi = __shfl(hi, src, 64);
  return ((u64)(u32)hi << 32) | (u32)lo;
}

// ---------------- 0. weight transpose FUSED with hist/state zeroing ----------------
// Blocks 0..143: wtr (w[oc][ic*9+tap] -> wT[ic*9+tap][oc]); blocks 144..183:
// zero the 5x8192 hist slices + done counters + SelState. Saves 1 launch
// (~25us at measured launch overhead).
__global__ __launch_bounds__(256) void wtrz_k(const float* __restrict__ w, float* __restrict__ wT,
                                              u32* __restrict__ hist, u32* __restrict__ done,
                                              SelState* st) {
  int b = blockIdx.x;
  int tid = threadIdx.x;
  if (b < 144) {
    __shared__ float t[64][65];
    int kb = b % 36;
    int ob = b / 36;
    for (int it = 0; it < 16; it++) {
      int idx = it * 256 + tid;
      int row = idx >> 6, colk = idx & 63;
      t[row][colk] = w[(size_t)(ob * 64 + row) * 2304 + kb * 64 + colk];
    }
    __syncthreads();
    for (int it = 0; it < 16; it++) {
      int idx = it * 256 + tid;
      int krow = idx >> 6, occ = idx & 63;
      wT[(size_t)(kb * 64 + krow) * 256 + ob * 64 + occ] = t[occ][krow];
    }
  } else {
    int zb = (b - 144) * 1024 + tid * 4;      // 40 blocks x 1024 = 40960 = 5*8192
    *(uint4*)&hist[zb] = make_uint4(0, 0, 0, 0);
    if (b == 144 && tid < 8) done[tid] = 0;
    if (b == 144 && tid == 0) { st->prefix = 0; st->r = K_SEL; st->cnt = 0; }
  }
}

// ---------------- 1. conv3x3 + bias + relu (R1 scalar-weight, validated local optimum) ----------------
// 7-round conv ledger: R1 scalar-weight = 510us/55% (best); all-LDS 573;
// 8x8 regtile 618 (write conflicts); 1-wave 1055 (spill); 8x4 617; LDS-
// broadcast weights 594/52%. Conv frozen. R9 lesson: cooperative grid.sync
// costs ~20-30us each on 8 non-coherent XCDs -> never again; launch-count
// reduction must use stream order + last-block patterns.
__global__ __launch_bounds__(256) void conv_k(const float* __restrict__ feat,
                                              const float* __restrict__ wT,
                                              const float* __restrict__ bias,
                                              float* __restrict__ outp) {
  int bx = blockIdx.x;              // 800 = 5 * 40 * 4
  int ct = bx % 5;
  int rt = (bx / 5) % 40;
  int ot = bx / 200;
  int x0 = ct * 32, y0 = rt * 4, oc0 = ot * 64;

  __shared__ float ps[2][8][6][36];

  int tid = threadIdx.x;
  int lane = tid & 63;
  int wvu = __builtin_amdgcn_readfirstlane(tid >> 6);   // wave id, SGPR-uniform
  int col = lane & 31;
  int s = lane >> 5;
  int ocw = oc0 + wvu * 16;

  // precompute staging map (constant over chunks): it 0..5 all threads, it 6 tid<96
  int s_off[7]; int s_lof[7]; bool s_val[7];
#pragma unroll
  for (int it = 0; it < 7; it++) {
    int idx = tid + it * 256;
    bool ex = (idx < 1632);
    int icl = idx / 204, rem = idx % 204;
    int r = rem / 34, c = rem % 34;
    int gy = y0 + r - 1, gx = x0 + c - 1;
    s_val[it] = ex && ((unsigned)gy < 160u) && ((unsigned)gx < 160u);
    s_off[it] = icl * NPX + gy * WW + gx;
    s_lof[it] = ex ? ((icl * 6 + r) * 36 + c) : 0;
    if (!ex) s_lof[it] = -1;
  }

  float acc0[16], acc1[16];
#pragma unroll
  for (int i = 0; i < 16; i++) { acc0[i] = 0.f; acc1[i] = 0.f; }

  float st[7];
  // stage chunk 0 into ps[0]
#pragma unroll
  for (int it = 0; it < 7; it++) {
    float v = 0.f;
    if (s_val[it]) v = feat[s_off[it]];
    if (s_lof[it] >= 0) (&ps[0][0][0][0])[s_lof[it]] = v;
  }
  __syncthreads();

  for (int c8 = 0; c8 < 32; c8++) {
    // issue global loads for next chunk (overlap with compute below)
    if (c8 < 31) {
      int icn = (c8 + 1) * 8;
#pragma unroll
      for (int it = 0; it < 7; it++) {
        st[it] = 0.f;
        if (s_val[it]) st[it] = feat[icn * NPX + s_off[it]];
      }
    }
    int buf = c8 & 1;
    int ic0 = c8 * 8;
    for (int icl = 0; icl < 8; icl++) {       // not unrolled: I-cache
      float p[4][3];
#pragma unroll
      for (int rr = 0; rr < 4; rr++)
#pragma unroll
        for (int cc = 0; cc < 3; cc++)
          p[rr][cc] = ps[buf][icl][2 * s + rr][col + cc];
      const float* wb = wT + (size_t)(ic0 + icl) * 9 * 256 + ocw;   // uniform addr
#pragma unroll
      for (int dy = 0; dy < 3; dy++) {
#pragma unroll
        for (int dx = 0; dx < 3; dx++) {
          const float* wr = wb + (dy * 3 + dx) * 256;
#pragma unroll
          for (int i = 0; i < 16; i++) {
            float wv_ = wr[i];                // s_load -> SGPR operand
            acc0[i] += wv_ * p[dy][dx];
            acc1[i] += wv_ * p[dy + 1][dx];
          }
        }
      }
    }
    if (c8 < 31) {
      __syncthreads();                        // everyone done reading ps[buf^1]
      float* dst = &ps[buf ^ 1][0][0][0];
#pragma unroll
      for (int it = 0; it < 7; it++)
        if (s_lof[it] >= 0) dst[s_lof[it]] = st[it];
      __syncthreads();                        // writes visible
    }
  }
#pragma unroll
  for (int i = 0; i < 16; i++) {
    int oc = ocw + i;
    float bv = bias[oc];
    size_t base = (size_t)oc * NPX + (y0 + 2 * s) * WW + x0 + col;
    outp[base] = fmaxf(acc0[i] + bv, 0.f);
    outp[base + WW] = fmaxf(acc1[i] + bv, 0.f);
  }
}

// ---------------- 2. heads + sigmoid + decode + clip + key ----------------
__global__ __launch_bounds__(256) void heads_k(const float* __restrict__ rpn,
                                               const float* __restrict__ cls_w,
                                               const float* __restrict__ cls_b,
                                               const float* __restrict__ bbox_w,
                                               const float* __restrict__ bbox_b,
                                               float4* __restrict__ boxes,
                                               float* __restrict__ scores,
                                               u64* __restrict__ keys) {
  __shared__ float sf[32][260];
  __shared__ float so[45][33];
  int tid = threadIdx.x;
  int px0 = blockIdx.x * 32;
  for (int idx = tid; idx < 8192; idx += 256) {
    int c = idx >> 5, p = idx & 31;
    sf[p][c] = rpn[(size_t)c * NPX + px0 + p];
  }
  __syncthreads();
  int p = tid & 31, g = tid >> 5;
  for (int oi = 0; oi < 6; oi++) {
    int o = g + oi * 8;
    if (o >= 45) break;
    const float* wr = (o < 9) ? (cls_w + o * CC) : (bbox_w + (o - 9) * CC);
    float bsum = (o < 9) ? cls_b[o] : bbox_b[o - 9];
    float s = 0.f;
    for (int c = 0; c < CC; c += 4) {
      float4 f = *(const float4*)&sf[p][c];
      float4 wv = *(const float4*)&wr[c];
      s += f.x * wv.x; s += f.y * wv.y; s += f.z * wv.z; s += f.w * wv.w;
    }
    so[o][p] = s + bsum;
  }
  __syncthreads();
  for (int t = tid; t < 288; t += 256) {
    int a = t >> 5, pp = t & 31;
    int px = px0 + pp;
    int y = px / 160, x = px - y * 160;
    float logit = so[a][pp];
    float sc = 1.f / (1.f + expf(-logit));
    float ddx = so[9 + 4 * a][pp], ddy = so[10 + 4 * a][pp];
    float ddw = fminf(so[11 + 4 * a][pp], DWH);
    float ddh = fminf(so[12 + 4 * a][pp], DWH);
    float ax1 = x * 16.f + c_bx1[a];
    float ay1 = y * 16.f + c_by1[a];
    float ax2 = x * 16.f + c_bx2[a];
    float ay2 = y * 16.f + c_by2[a];
    float aw = ax2 - ax1, ah = ay2 - ay1;
    float cx = ax1 + 0.5f * aw, cy = ay1 + 0.5f * ah;
    float pcx = ddx * aw + cx, pcy = ddy * ah + cy;
    float pw = expf(ddw) * aw, phh = expf(ddh) * ah;
    float x1 = pcx - 0.5f * pw, y1 = pcy - 0.5f * phh;
    float x2 = pcx + 0.5f * pw, y2 = pcy + 0.5f * phh;
    x1 = fminf(fmaxf(x1, 0.f), IMS); x2 = fminf(fmaxf(x2, 0.f), IMS);
    y1 = fminf(fmaxf(y1, 0.f), IMS); y2 = fminf(fmaxf(y2, 0.f), IMS);
    int gidx = px * 9 + a;
    boxes[gidx] = make_float4(x1, y1, x2, y2);
    scores[gidx] = sc;
    u32 sb = __float_as_uint(sc);
    u32 mono = (sb & 0x80000000u) ? ~sb : (sb | 0x80000000u);
    keys[gidx] = ((u64)mono << 32) | (u64)(0xFFFFFFFFu - (u32)gidx);
  }
}

// ---------------- 3. grid-wide radix pass with LAST-BLOCK fused scan ----------------
// R8 split hist and scan into 2 launches/pass (10 total). Here the block that
// finishes last (device-scope done-counter handshake) performs the scan in
// the same kernel: 5 launches total. Visibility discipline (G16): every block
// __threadfence()s its hist atomics before atomicAdd(done); the scanning
// block reads bins with __hip_atomic_load(AGENT scope) -> coherent across
// XCDs. Scan walk retiled for 256 threads but bin-for-bin identical to R8's
// -> same {prefix, r} -> same selk set -> absmax 0.0.
__global__ __launch_bounds__(256) void hist_k(const u64* __restrict__ keys,
                                              SelState* st,
                                              u32* __restrict__ gh,
                                              u32* __restrict__ done,
                                              int wbits, int bitsdone, int pass) {
  __shared__ u32 sl[8192];
  __shared__ u32 tsum[256];
  __shared__ u32 wsum[4];
  __shared__ int islast;
  int tid = threadIdx.x;
  int idx = blockIdx.x * 256 + tid;          // grid 900 -> exactly 230400
  int lane = tid & 63;
  int nbins = 1 << wbits;
  u64 k = keys[idx];
  int shift = 64 - bitsdone - wbits;
  bool active = true;
  if (bitsdone > 0) active = ((k >> (64 - bitsdone)) == st->prefix);
  u32 digit = (u32)((k >> shift) & (u64)(nbins - 1));
  u64 act = __ballot(active);
  u64 todo = act;
  while (todo) {
    int src = __builtin_ctzll(todo);
    u32 d0 = (u32)__shfl((int)digit, src, 64);
    u64 m = __ballot(digit == d0) & act;
    if (lane == src) atomicAdd(&gh[d0], (u32)__popcll(m & todo));
    todo &= ~m;
  }
  __syncthreads();
  if (tid == 0) {
    __threadfence();                         // my atomics visible device-wide
    u32 prev = atomicAdd(&done[pass], 1u);
    islast = (prev == 899);
  }
  __syncthreads();
  if (!islast) return;

  // ---- scan (last block only): coherent bin read, then R8 walk ----
  for (int i = tid; i < nbins; i += 256)
    sl[i] = __hip_atomic_load(&gh[i], __ATOMIC_RELAXED, __HIP_MEMORY_SCOPE_AGENT);
  __syncthreads();
  int bpt = nbins >> 8;                      // 32 (13-bit) / 16 (12-bit)
  u32 r = st->r;
  u32 s = 0;
  for (int b = 0; b < bpt; b++) s += sl[tid * bpt + b];
  tsum[tid] = s;
  u32 v = s;
#pragma unroll
  for (int off = 1; off < 64; off <<= 1) v += (u32)__shfl_xor((int)v, off, 64);
  if (lane == 0) wsum[tid >> 6] = v;
  __syncthreads();
  if (tid == 0) {
    u32 cum = 0;
    int ws = 3;
    while (ws > 0 && cum + wsum[ws] < r) { cum += wsum[ws]; ws--; }
    int t = ws * 64 + 63, tend = ws * 64;
    while (t > tend && cum + tsum[t] < r) { cum += tsum[t]; t--; }
    int b = t * bpt + bpt - 1, bend = t * bpt;
    while (b > bend && cum + sl[b] < r) { cum += sl[b]; b--; }
    st->prefix = (st->prefix << wbits) | (u64)(u32)b;
    st->r = r - cum;
  }
}

__global__ __launch_bounds__(256) void compact_k(const u64* __restrict__ keys,
                                                 SelState* st, u64* __restrict__ selk) {
  int idx = blockIdx.x * 256 + threadIdx.x;
  u64 k = keys[idx];
  if (k >= st->prefix) {
    u32 pos = atomicAdd(&st->cnt, 1u);
    selk[pos] = k;
  }
}

// ---------------- 4. exact rank -> sorted SoA ----------------
__global__ __launch_bounds__(64) void rank_k(const u64* __restrict__ selk,
                                             const float4* __restrict__ boxes,
                                             const float* __restrict__ scores,
                                             float* sx1, float* sy1, float* sx2, float* sy2, float* ssc) {
  __shared__ __align__(16) u64 sk[SEL_PAD];
  int lane = threadIdx.x;
  for (int i = lane; i < SEL_PAD; i += 64) sk[i] = (i < K_SEL) ? selk[i] : 0ull;
  __syncthreads();
  int n = blockIdx.x * 64 + lane;
  u64 myk = (n < K_SEL) ? selk[n] : ~0ull;
  int cnt = 0;
  const ulonglong2* sk2 = (const ulonglong2*)sk;
#pragma unroll 8
  for (int j = 0; j < SEL_PAD / 2; j++) {
    ulonglong2 kk = sk2[j];
    cnt += (kk.x > myk) ? 1 : 0;
    cnt += (kk.y > myk) ? 1 : 0;
  }
  if (n < K_SEL) {
    u32 oidx = 0xFFFFFFFFu - (u32)(myk & 0xFFFFFFFFull);
    float4 b = boxes[oidx];
    sx1[cnt] = b.x; sy1[cnt] = b.y; sx2[cnt] = b.z; sy2[cnt] = b.w;
    ssc[cnt] = scores[oidx];
  }
}

// ---------------- 5. pairwise suppression mask (column-major) ----------------
__global__ __launch_bounds__(256) void mask_k(const float* __restrict__ sx1, const float* __restrict__ sy1,
                                              const float* __restrict__ sx2, const float* __restrict__ sy2,
                                              u64* __restrict__ maskT) {
  __shared__ float jb[5][3008];
  int tid = threadIdx.x;
  int wv = tid >> 6, lane = tid & 63;
  int ibase = blockIdx.x * 32 + wv * 8;
  float ix1[8], iy1[8], ix2[8], iy2[8], ia[8];
#pragma unroll
  for (int r = 0; r < 8; r++) {
    int i = ibase + r;
    ix1[r] = sx1[i]; iy1[r] = sy1[i]; ix2[r] = sx2[i]; iy2[r] = sy2[i];
    ia[r] = (ix2[r] - ix1[r]) * (iy2[r] - iy1[r]);
  }
  for (int half = 0; half < 2; half++) {
    int j0 = half * 3008;
    __syncthreads();
    for (int idx = tid; idx < 3008; idx += 256) {
      int j = j0 + idx;
      bool v = j < K_SEL;
      float a = v ? sx1[j] : 0.f;
      float b = v ? sy1[j] : 0.f;
      float c = v ? sx2[j] : 0.f;
      float d = v ? sy2[j] : 0.f;
      jb[0][idx] = a; jb[1][idx] = b; jb[2][idx] = c; jb[3][idx] = d;
      jb[4][idx] = (c - a) * (d - b);
    }
    __syncthreads();
    for (int wi = 0; wi < 47; wi++) {
      int w = half * 47 + wi;
      int jl = wi * 64 + lane;
      int j = j0 + jl;
      float jx1 = jb[0][jl], jy1 = jb[1][jl], jx2 = jb[2][jl], jy2 = jb[3][jl], ja = jb[4][jl];
      bool jv = j < K_SEL;
#pragma unroll
      for (int r = 0; r < 8; r++) {
        int i = ibase + r;
        float xl = fmaxf(ix1[r], jx1), yt = fmaxf(iy1[r], jy1);
        float xr = fminf(ix2[r], jx2), yb = fminf(iy2[r], jy2);
        float iw = fmaxf(xr - xl, 0.f), ihh = fmaxf(yb - yt, 0.f);
        float inter = iw * ihh;
        bool sup = jv && (j > i) && (inter > 0.7f * (ia[r] + ja - inter));
        u64 bits = __ballot(sup);
        if (lane == 0 && i < K_SEL) maskT[(size_t)w * SEL_PAD + i] = bits;
      }
    }
  }
}

// ---------------- 6. greedy NMS + finalize FUSED (1 block x 16 waves) ----------------
// nms is single-block and holds kept-bits (skept) in LDS; the finalize phase
// runs in the same block after a barrier -> saves 1 launch + the alive[]
// global round-trip. Output values identical to the split version.
__global__ __launch_bounds__(1024) void nmsf_k(const u64* __restrict__ maskT,
                                               const float* __restrict__ sx1, const float* __restrict__ sy1,
                                               const float* __restrict__ sx2, const float* __restrict__ sy2,
                                               const float* __restrict__ ssc, float* __restrict__ out) {
  __shared__ u64 sdiag[94 * 64];
  __shared__ u64 skept[96];
  __shared__ u64 svalid[94];
  __shared__ u64 wacc[16];
  __shared__ u32 pre[95];
  int tid = threadIdx.x;
  int wv = tid >> 6, lane = tid & 63;

  if (tid < 96) skept[tid] = 0ull;
  for (int w = wv; w < 94; w += 16) {
    int p = w * 64 + lane;
    float bw = sx2[p] - sx1[p], bh = sy2[p] - sy1[p];
    bool ok = (p < K_SEL) && (bw >= 16.f) && (bh >= 16.f);
    u64 bits = __ballot(ok);
    if (lane == 0) svalid[w] = bits;
  }
  for (int idx = tid; idx < 94 * 64; idx += 1024) {
    int cc = idx >> 6;
    sdiag[idx] = maskT[(size_t)cc * SEL_PAD + cc * 64 + (idx & 63)];
  }
  __syncthreads();

  for (int c = 0; c < 94; c++) {
    size_t colbase = (size_t)c * SEL_PAD;
    int i0 = 2 * tid;
    ulonglong2 v0 = *(const ulonglong2*)&maskT[colbase + i0];
    ulonglong2 v1 = *(const ulonglong2*)&maskT[colbase + i0 + 2048];
    ulonglong2 v2 = *(const ulonglong2*)&maskT[colbase + i0 + 4096];
    u64 k0 = skept[i0 >> 6];
    u64 k1 = skept[(i0 + 2048) >> 6];
    u64 k2 = skept[(i0 + 4096) >> 6];
    int sh = i0 & 63;
    u64 acc = 0;
    if ((k0 >> sh) & 1) acc |= v0.x;
    if ((k0 >> (sh + 1)) & 1) acc |= v0.y;
    if ((k1 >> sh) & 1) acc |= v1.x;
    if ((k1 >> (sh + 1)) & 1) acc |= v1.y;
    if ((k2 >> sh) & 1) acc |= v2.x;
    if ((k2 >> (sh + 1)) & 1) acc |= v2.y;
    u32 lo = (u32)acc, hi = (u32)(acc >> 32);
#pragma unroll
    for (int off = 1; off < 64; off <<= 1) {
      lo |= (u32)__shfl_xor((int)lo, off, 64);
      hi |= (u32)__shfl_xor((int)hi, off, 64);
    }
    if (lane == 0) wacc[wv] = ((u64)hi << 32) | (u64)lo;
    __syncthreads();
    if (wv == 0) {
      u64 a = wacc[lane & 15];
      u32 alo = (u32)a, ahi = (u32)(a >> 32);
#pragma unroll
      for (int off = 1; off < 16; off <<= 1) {
        alo |= (u32)__shfl_xor((int)alo, off, 64);
        ahi |= (u32)__shfl_xor((int)ahi, off, 64);
      }
      u64 supp = ((u64)ahi << 32) | (u64)alo;
      u64 cur = svalid[c] & ~supp;
      u64 d = sdiag[c * 64 + lane];
      u64 rem = cur, kept = 0;
      while (rem) {
        int b = __builtin_ctzll(rem);
        kept |= (1ull << b);
        u64 dead = shfl64(d, b);
        rem &= ~dead;
        rem &= ~(1ull << b);
      }
      if (lane == 0) skept[c] = kept;
    }
    __syncthreads();
  }

  // ---- finalize phase (uses skept in LDS; identical outputs to final_k) ----
  if (tid == 0) {
    u32 s = 0;
    for (int w = 0; w < 94; w++) { pre[w] = s; s += (u32)__popcll(skept[w]); }
    pre[94] = s;
  }
  __syncthreads();
  u32 total = pre[94];
  for (int p = tid; p < K_SEL; p += 1024) {
    int w = p >> 6, b = p & 63;
    u64 word = skept[w];
    u32 kb = pre[w] + (u32)__popcll(word & ((1ull << b) - 1ull));
    bool kept = (word >> b) & 1ull;
    int slot = -1; float sc = -1.f;
    if (kept) {
      if (kb < 300) { slot = (int)kb; sc = ssc[p]; }
    } else {
      u32 s2 = total + (u32)p - kb;
      if (s2 < 300) slot = (int)s2;
    }
    if (slot >= 0) {
      out[slot * 5 + 0] = sx1[p];
      out[slot * 5 + 1] = sy1[p];
      out[slot * 5 + 2] = sx2[p];
      out[slot * 5 + 3] = sy2[p];
      out[slot * 5 + 4] = sc;
    }
  }
}

extern "C" void kernel_launch(void* const* d_in, const int* in_sizes, int n_in,
                              void* d_out, int out_size, void* d_ws, size_t ws_size,
                              hipStream_t stream) {
  const float* feat   = (const float*)d_in[0];
  const float* conv_w = (const float*)d_in[2];
  const float* conv_b = (const float*)d_in[3];
  const float* cls_w  = (const float*)d_in[4];
  const float* cls_b  = (const float*)d_in[5];
  const float* bbox_w = (const float*)d_in[6];
  const float* bbox_b = (const float*)d_in[7];
  float* out = (float*)d_out;
  char* ws = (char*)d_ws;

  float*  rpn    = (float*)(ws + OFF_RPN);
  float4* boxes  = (float4*)(ws + OFF_BOXES);
  float*  scores = (float*)(ws + OFF_SCORES);
  u64*    keys   = (u64*)(ws + OFF_KEYS);
  SelState* st   = (SelState*)(ws + OFF_STATE);
  u64*    selk   = (u64*)(ws + OFF_SELK);
  float*  sx1    = (float*)(ws + OFF_SX1);
  float*  sy1    = (float*)(ws + OFF_SY1);
  float*  sx2    = (float*)(ws + OFF_SX2);
  float*  sy2    = (float*)(ws + OFF_SY2);
  float*  ssc    = (float*)(ws + OFF_SSC);
  u64*    maskT  = (u64*)(ws + OFF_MASKT);
  float*  wT     = (float*)(ws + OFF_WT);
  u32*    hist   = (u32*)(ws + OFF_HIST);
  u32*    done   = (u32*)(ws + OFF_DONE);

  wtrz_k<<<184, 256, 0, stream>>>(conv_w, wT, hist, done, st);
  conv_k<<<800, 256, 0, stream>>>(feat, wT, conv_b, rpn);
  heads_k<<<800, 256, 0, stream>>>(rpn, cls_w, cls_b, bbox_w, bbox_b, boxes, scores, keys);

  hist_k<<<900, 256, 0, stream>>>(keys, st, hist,         done, 13,  0, 0);
  hist_k<<<900, 256, 0, stream>>>(keys, st, hist +  8192, done, 13, 13, 1);
  hist_k<<<900, 256, 0, stream>>>(keys, st, hist + 16384, done, 13, 26, 2);
  hist_k<<<900, 256, 0, stream>>>(keys, st, hist + 24576, done, 13, 39, 3);
  hist_k<<<900, 256, 0, stream>>>(keys, st, hist + 32768, done, 12, 52, 4);

  compact_k<<<900, 256, 0, stream>>>(keys, st, selk);
  rank_k<<<94, 64, 0, stream>>>(selk, boxes, scores, sx1, sy1, sx2, sy2, ssc);
  mask_k<<<188, 256, 0, stream>>>(sx1, sy1, sx2, sy2, maskT);
  nmsf_k<<<1, 1024, 0, stream>>>(maskT, sx1, sy1, sx2, sy2, ssc, out);
}

// Round 11
// 1400.224 us; speedup vs baseline: 1.1663x; 1.0947x over previous
//
#include <hip/hip_runtime.h>
#include <math.h>

typedef unsigned long long u64;
typedef unsigned int u32;

#define HH 160
#define WW 160
#define CC 256
#define NPX 25600
#define NA 9
#define NSC 230400
#define K_SEL 6000
#define SEL_PAD 6016
#define IMS 2560.0f
#define DWH 4.135166556742356f

struct SelState { u64 prefix; u32 r; u32 cnt; };

// ---- ws layout (bytes) ----
#define OFF_BOXES   0u               // float4[230400] -> 3,686,400
#define OFF_SCORES  3686400u         // float [230400]
#define OFF_KEYS    4608000u         // u64   [230400]
#define OFF_STATE   7499776u
#define OFF_SELK    7500032u         // u64[6016]
#define OFF_SX1     7548160u
#define OFF_SY1     7572224u
#define OFF_SX2     7596288u
#define OFF_SY2     7620352u
#define OFF_SSC     7644416u
#define OFF_ALIVE   7668480u
#define OFF_MASKT   11503104u        // u64[94*6016 + 128 pad] -> ends 16,028,160
#define OFF_WT      16028160u        // float[2304*256] -> ends 18,387,456
#define OFF_HIST    18387456u        // u32[5*8192] -> ends 18,551,296
#define OFF_RPN     27869184u        // float[256*160*160] -> ends 54,083,584

__constant__ float c_bx1[9] = {-91.f,-181.f,-362.f,-64.f,-128.f,-256.f,-45.f,-91.f,-181.f};
__constant__ float c_by1[9] = {-45.f,-91.f,-181.f,-64.f,-128.f,-256.f,-91.f,-181.f,-362.f};
__constant__ float c_bx2[9] = { 91.f, 181.f, 362.f, 64.f, 128.f, 256.f, 45.f, 91.f, 181.f};
__constant__ float c_by2[9] = { 45.f,  91.f, 181.f, 64.f, 128.f, 256.f, 91.f, 181.f, 362.f};

__device__ inline u64 shfl64(u64 v, int src) {
  int lo = (int)(v & 0xFFFFFFFFull), hi = (int)(v >> 32);
  lo = __shfl(lo, src, 64); hi = __shfl(hi, src, 64);
  return ((u64)(u32)hi << 32) | (u32)lo;
}

// ---------------- 0. weight transpose FUSED with hist/state zeroing ----------------
// Blocks 0..143: wtr; blocks 144..183: zero 5x8192 hist + SelState.
// (R10-proven fusion; identical work to split version.)
__global__ __launch_bounds__(256) void wtrz_k(const float* __restrict__ w, float* __restrict__ wT,
                                              u32* __restrict__ hist, SelState* st) {
  int b = blockIdx.x;
  int tid = threadIdx.x;
  if (b < 144) {
    __shared__ float t[64][65];
    int kb = b % 36;
    int ob = b / 36;
    for (int it = 0; it < 16; it++) {
      int idx = it * 256 + tid;
      int row = idx >> 6, colk = idx & 63;
      t[row][colk] = w[(size_t)(ob * 64 + row) * 2304 + kb * 64 + colk];
    }
    __syncthreads();
    for (int it = 0; it < 16; it++) {
      int idx = it * 256 + tid;
      int krow = idx >> 6, occ = idx & 63;
      wT[(size_t)(kb * 64 + krow) * 256 + ob * 64 + occ] = t[occ][krow];
    }
  } else {
    int zb = (b - 144) * 1024 + tid * 4;      // 40 blocks x 1024 = 40960 = 5*8192
    *(uint4*)&hist[zb] = make_uint4(0, 0, 0, 0);
    if (b == 144 && tid == 0) { st->prefix = 0; st->r = K_SEL; st->cnt = 0; }
  }
}

// ---------------- 1. conv3x3 + bias + relu (R1 scalar-weight, frozen) ----------------
// Launch-overhead model resolved over R8/R9/R10: launches are cheap (graph);
// R9 grid.sync ~ +20us each; R10's last-block hist fusion ~ +20us/pass.
// Structure fusions must add ZERO per-kernel cost to pay off.
__global__ __launch_bounds__(256) void conv_k(const float* __restrict__ feat,
                                              const float* __restrict__ wT,
                                              const float* __restrict__ bias,
                                              float* __restrict__ outp) {
  int bx = blockIdx.x;              // 800 = 5 * 40 * 4
  int ct = bx % 5;
  int rt = (bx / 5) % 40;
  int ot = bx / 200;
  int x0 = ct * 32, y0 = rt * 4, oc0 = ot * 64;

  __shared__ float ps[2][8][6][36];

  int tid = threadIdx.x;
  int lane = tid & 63;
  int wvu = __builtin_amdgcn_readfirstlane(tid >> 6);   // wave id, SGPR-uniform
  int col = lane & 31;
  int s = lane >> 5;
  int ocw = oc0 + wvu * 16;

  // precompute staging map (constant over chunks): it 0..5 all threads, it 6 tid<96
  int s_off[7]; int s_lof[7]; bool s_val[7];
#pragma unroll
  for (int it = 0; it < 7; it++) {
    int idx = tid + it * 256;
    bool ex = (idx < 1632);
    int icl = idx / 204, rem = idx % 204;
    int r = rem / 34, c = rem % 34;
    int gy = y0 + r - 1, gx = x0 + c - 1;
    s_val[it] = ex && ((unsigned)gy < 160u) && ((unsigned)gx < 160u);
    s_off[it] = icl * NPX + gy * WW + gx;
    s_lof[it] = ex ? ((icl * 6 + r) * 36 + c) : 0;
    if (!ex) s_lof[it] = -1;
  }

  float acc0[16], acc1[16];
#pragma unroll
  for (int i = 0; i < 16; i++) { acc0[i] = 0.f; acc1[i] = 0.f; }

  float st[7];
  // stage chunk 0 into ps[0]
#pragma unroll
  for (int it = 0; it < 7; it++) {
    float v = 0.f;
    if (s_val[it]) v = feat[s_off[it]];
    if (s_lof[it] >= 0) (&ps[0][0][0][0])[s_lof[it]] = v;
  }
  __syncthreads();

  for (int c8 = 0; c8 < 32; c8++) {
    // issue global loads for next chunk (overlap with compute below)
    if (c8 < 31) {
      int icn = (c8 + 1) * 8;
#pragma unroll
      for (int it = 0; it < 7; it++) {
        st[it] = 0.f;
        if (s_val[it]) st[it] = feat[icn * NPX + s_off[it]];
      }
    }
    int buf = c8 & 1;
    int ic0 = c8 * 8;
    for (int icl = 0; icl < 8; icl++) {       // not unrolled: I-cache
      float p[4][3];
#pragma unroll
      for (int rr = 0; rr < 4; rr++)
#pragma unroll
        for (int cc = 0; cc < 3; cc++)
          p[rr][cc] = ps[buf][icl][2 * s + rr][col + cc];
      const float* wb = wT + (size_t)(ic0 + icl) * 9 * 256 + ocw;   // uniform addr
#pragma unroll
      for (int dy = 0; dy < 3; dy++) {
#pragma unroll
        for (int dx = 0; dx < 3; dx++) {
          const float* wr = wb + (dy * 3 + dx) * 256;
#pragma unroll
          for (int i = 0; i < 16; i++) {
            float wv_ = wr[i];                // s_load -> SGPR operand
            acc0[i] += wv_ * p[dy][dx];
            acc1[i] += wv_ * p[dy + 1][dx];
          }
        }
      }
    }
    if (c8 < 31) {
      __syncthreads();                        // everyone done reading ps[buf^1]
      float* dst = &ps[buf ^ 1][0][0][0];
#pragma unroll
      for (int it = 0; it < 7; it++)
        if (s_lof[it] >= 0) dst[s_lof[it]] = st[it];
      __syncthreads();                        // writes visible
    }
  }
#pragma unroll
  for (int i = 0; i < 16; i++) {
    int oc = ocw + i;
    float bv = bias[oc];
    size_t base = (size_t)oc * NPX + (y0 + 2 * s) * WW + x0 + col;
    outp[base] = fmaxf(acc0[i] + bv, 0.f);
    outp[base + WW] = fmaxf(acc1[i] + bv, 0.f);
  }
}

// ---------------- 2. heads + sigmoid + decode + clip + key ----------------
__global__ __launch_bounds__(256) void heads_k(const float* __restrict__ rpn,
                                               const float* __restrict__ cls_w,
                                               const float* __restrict__ cls_b,
                                               const float* __restrict__ bbox_w,
                                               const float* __restrict__ bbox_b,
                                               float4* __restrict__ boxes,
                                               float* __restrict__ scores,
                                               u64* __restrict__ keys) {
  __shared__ float sf[32][260];
  __shared__ float so[45][33];
  int tid = threadIdx.x;
  int px0 = blockIdx.x * 32;
  for (int idx = tid; idx < 8192; idx += 256) {
    int c = idx >> 5, p = idx & 31;
    sf[p][c] = rpn[(size_t)c * NPX + px0 + p];
  }
  __syncthreads();
  int p = tid & 31, g = tid >> 5;
  for (int oi = 0; oi < 6; oi++) {
    int o = g + oi * 8;
    if (o >= 45) break;
    const float* wr = (o < 9) ? (cls_w + o * CC) : (bbox_w + (o - 9) * CC);
    float bsum = (o < 9) ? cls_b[o] : bbox_b[o - 9];
    float s = 0.f;
    for (int c = 0; c < CC; c += 4) {
      float4 f = *(const float4*)&sf[p][c];
      float4 wv = *(const float4*)&wr[c];
      s += f.x * wv.x; s += f.y * wv.y; s += f.z * wv.z; s += f.w * wv.w;
    }
    so[o][p] = s + bsum;
  }
  __syncthreads();
  for (int t = tid; t < 288; t += 256) {
    int a = t >> 5, pp = t & 31;
    int px = px0 + pp;
    int y = px / 160, x = px - y * 160;
    float logit = so[a][pp];
    float sc = 1.f / (1.f + expf(-logit));
    float ddx = so[9 + 4 * a][pp], ddy = so[10 + 4 * a][pp];
    float ddw = fminf(so[11 + 4 * a][pp], DWH);
    float ddh = fminf(so[12 + 4 * a][pp], DWH);
    float ax1 = x * 16.f + c_bx1[a];
    float ay1 = y * 16.f + c_by1[a];
    float ax2 = x * 16.f + c_bx2[a];
    float ay2 = y * 16.f + c_by2[a];
    float aw = ax2 - ax1, ah = ay2 - ay1;
    float cx = ax1 + 0.5f * aw, cy = ay1 + 0.5f * ah;
    float pcx = ddx * aw + cx, pcy = ddy * ah + cy;
    float pw = expf(ddw) * aw, phh = expf(ddh) * ah;
    float x1 = pcx - 0.5f * pw, y1 = pcy - 0.5f * phh;
    float x2 = pcx + 0.5f * pw, y2 = pcy + 0.5f * phh;
    x1 = fminf(fmaxf(x1, 0.f), IMS); x2 = fminf(fmaxf(x2, 0.f), IMS);
    y1 = fminf(fmaxf(y1, 0.f), IMS); y2 = fminf(fmaxf(y2, 0.f), IMS);
    int gidx = px * 9 + a;
    boxes[gidx] = make_float4(x1, y1, x2, y2);
    scores[gidx] = sc;
    u32 sb = __float_as_uint(sc);
    u32 mono = (sb & 0x80000000u) ? ~sb : (sb | 0x80000000u);
    keys[gidx] = ((u64)mono << 32) | (u64)(0xFFFFFFFFu - (u32)gidx);
  }
}

// ---------------- 3. grid-wide radix select (R8 split hist/scan, RESTORED) ----------------
// R10's last-block fused scan regressed +102us (33KB LDS in all 900 blocks +
// per-block device fences). Split version measured fastest (R8 = 1431 total).
__global__ __launch_bounds__(256) void hist_k(const u64* __restrict__ keys,
                                              const SelState* __restrict__ st,
                                              u32* __restrict__ hist,
                                              int wbits, int bitsdone) {
  int idx = blockIdx.x * 256 + threadIdx.x;  // grid 900 -> exactly 230400
  int lane = threadIdx.x & 63;
  u64 k = keys[idx];
  int shift = 64 - bitsdone - wbits;
  bool active = true;
  if (bitsdone > 0) active = ((k >> (64 - bitsdone)) == st->prefix);
  u32 digit = (u32)((k >> shift) & (u64)((1 << wbits) - 1));
  u64 act = __ballot(active);
  u64 todo = act;
  while (todo) {
    int src = __builtin_ctzll(todo);
    u32 d0 = (u32)__shfl((int)digit, src, 64);
    u64 m = __ballot(digit == d0) & act;
    if (lane == src) atomicAdd(&hist[d0], (u32)__popcll(m & todo));
    todo &= ~m;
  }
}

__global__ __launch_bounds__(1024) void scan_k(const u32* __restrict__ hist,
                                               SelState* st, int wbits) {
  __shared__ u32 tsum[1024];
  __shared__ u32 wsum[16];
  int tid = threadIdx.x;
  int lane = tid & 63, wv = tid >> 6;
  int nbins = 1 << wbits;
  int bpt = nbins >> 10;
  u32 r = st->r;
  u32 s = 0;
  for (int b = 0; b < bpt; b++) s += hist[tid * bpt + b];
  tsum[tid] = s;
  u32 v = s;
#pragma unroll
  for (int off = 1; off < 64; off <<= 1) v += (u32)__shfl_xor((int)v, off, 64);
  if (lane == 0) wsum[wv] = v;
  __syncthreads();
  if (tid == 0) {
    u32 cum = 0;
    int ws = 15;
    while (ws > 0 && cum + wsum[ws] < r) { cum += wsum[ws]; ws--; }
    int t = ws * 64 + 63, tend = ws * 64;
    while (t > tend && cum + tsum[t] < r) { cum += tsum[t]; t--; }
    int b = t * bpt + bpt - 1, bend = t * bpt;
    while (b > bend && cum + hist[b] < r) { cum += hist[b]; b--; }
    st->prefix = (st->prefix << wbits) | (u64)(u32)b;
    st->r = r - cum;
  }
}

// ---------------- 3b. compact: block-aggregated atomic ----------------
// Old: per-selected-lane atomicAdd to ONE address -> ~3000 serialized wave-
// atomics (~60us). New: wave ballot -> block scan in LDS -> ONE atomic per
// block (900 total). selk ORDER changes, but rank_k assigns output slots by
// exact key comparison -> selected SET identical (same 64-bit threshold) ->
// outputs bit-identical -> absmax 0.0.
__global__ __launch_bounds__(256) void compact_k(const u64* __restrict__ keys,
                                                 SelState* st, u64* __restrict__ selk) {
  __shared__ u32 wbase[4];
  __shared__ u32 blkbase;
  int tid = threadIdx.x;
  int lane = tid & 63, wv = tid >> 6;
  int idx = blockIdx.x * 256 + tid;
  u64 k = keys[idx];
  bool sel = (k >= st->prefix);
  u64 m = __ballot(sel);
  u32 wcnt = (u32)__popcll(m);
  u32 before = (u32)__popcll(m & ((1ull << lane) - 1ull));
  if (lane == 0) wbase[wv] = wcnt;
  __syncthreads();
  if (tid == 0) {
    u32 b0 = wbase[0], b1 = wbase[1], b2 = wbase[2], b3 = wbase[3];
    u32 tot = b0 + b1 + b2 + b3;
    blkbase = tot ? atomicAdd(&st->cnt, tot) : 0u;
    wbase[0] = 0; wbase[1] = b0; wbase[2] = b0 + b1; wbase[3] = b0 + b1 + b2;
  }
  __syncthreads();
  if (sel) selk[blkbase + wbase[wv] + before] = k;
}

// ---------------- 4. exact rank -> sorted SoA ----------------
__global__ __launch_bounds__(64) void rank_k(const u64* __restrict__ selk,
                                             const float4* __restrict__ boxes,
                                             const float* __restrict__ scores,
                                             float* sx1, float* sy1, float* sx2, float* sy2, float* ssc) {
  __shared__ __align__(16) u64 sk[SEL_PAD];
  int lane = threadIdx.x;
  for (int i = lane; i < SEL_PAD; i += 64) sk[i] = (i < K_SEL) ? selk[i] : 0ull;
  __syncthreads();
  int n = blockIdx.x * 64 + lane;
  u64 myk = (n < K_SEL) ? selk[n] : ~0ull;
  int cnt = 0;
  const ulonglong2* sk2 = (const ulonglong2*)sk;
#pragma unroll 8
  for (int j = 0; j < SEL_PAD / 2; j++) {
    ulonglong2 kk = sk2[j];
    cnt += (kk.x > myk) ? 1 : 0;
    cnt += (kk.y > myk) ? 1 : 0;
  }
  if (n < K_SEL) {
    u32 oidx = 0xFFFFFFFFu - (u32)(myk & 0xFFFFFFFFull);
    float4 b = boxes[oidx];
    sx1[cnt] = b.x; sy1[cnt] = b.y; sx2[cnt] = b.z; sy2[cnt] = b.w;
    ssc[cnt] = scores[oidx];
  }
}

// ---------------- 5. pairwise suppression mask (column-major) ----------------
__global__ __launch_bounds__(256) void mask_k(const float* __restrict__ sx1, const float* __restrict__ sy1,
                                              const float* __restrict__ sx2, const float* __restrict__ sy2,
                                              u64* __restrict__ maskT) {
  __shared__ float jb[5][3008];
  int tid = threadIdx.x;
  int wv = tid >> 6, lane = tid & 63;
  int ibase = blockIdx.x * 32 + wv * 8;
  float ix1[8], iy1[8], ix2[8], iy2[8], ia[8];
#pragma unroll
  for (int r = 0; r < 8; r++) {
    int i = ibase + r;
    ix1[r] = sx1[i]; iy1[r] = sy1[i]; ix2[r] = sx2[i]; iy2[r] = sy2[i];
    ia[r] = (ix2[r] - ix1[r]) * (iy2[r] - iy1[r]);
  }
  for (int half = 0; half < 2; half++) {
    int j0 = half * 3008;
    __syncthreads();
    for (int idx = tid; idx < 3008; idx += 256) {
      int j = j0 + idx;
      bool v = j < K_SEL;
      float a = v ? sx1[j] : 0.f;
      float b = v ? sy1[j] : 0.f;
      float c = v ? sx2[j] : 0.f;
      float d = v ? sy2[j] : 0.f;
      jb[0][idx] = a; jb[1][idx] = b; jb[2][idx] = c; jb[3][idx] = d;
      jb[4][idx] = (c - a) * (d - b);
    }
    __syncthreads();
    for (int wi = 0; wi < 47; wi++) {
      int w = half * 47 + wi;
      int jl = wi * 64 + lane;
      int j = j0 + jl;
      float jx1 = jb[0][jl], jy1 = jb[1][jl], jx2 = jb[2][jl], jy2 = jb[3][jl], ja = jb[4][jl];
      bool jv = j < K_SEL;
#pragma unroll
      for (int r = 0; r < 8; r++) {
        int i = ibase + r;
        float xl = fmaxf(ix1[r], jx1), yt = fmaxf(iy1[r], jy1);
        float xr = fminf(ix2[r], jx2), yb = fminf(iy2[r], jy2);
        float iw = fmaxf(xr - xl, 0.f), ihh = fmaxf(yb - yt, 0.f);
        float inter = iw * ihh;
        bool sup = jv && (j > i) && (inter > 0.7f * (ia[r] + ja - inter));
        u64 bits = __ballot(sup);
        if (lane == 0 && i < K_SEL) maskT[(size_t)w * SEL_PAD + i] = bits;
      }
    }
  }
}

// ---------------- 6. greedy NMS + finalize FUSED (1 block x 16 waves) ----------------
__global__ __launch_bounds__(1024) void nmsf_k(const u64* __restrict__ maskT,
                                               const float* __restrict__ sx1, const float* __restrict__ sy1,
                                               const float* __restrict__ sx2, const float* __restrict__ sy2,
                                               const float* __restrict__ ssc, float* __restrict__ out) {
  __shared__ u64 sdiag[94 * 64];
  __shared__ u64 skept[96];
  __shared__ u64 svalid[94];
  __shared__ u64 wacc[16];
  __shared__ u32 pre[95];
  int tid = threadIdx.x;
  int wv = tid >> 6, lane = tid & 63;

  if (tid < 96) skept[tid] = 0ull;
  for (int w = wv; w < 94; w += 16) {
    int p = w * 64 + lane;
    float bw = sx2[p] - sx1[p], bh = sy2[p] - sy1[p];
    bool ok = (p < K_SEL) && (bw >= 16.f) && (bh >= 16.f);
    u64 bits = __ballot(ok);
    if (lane == 0) svalid[w] = bits;
  }
  for (int idx = tid; idx < 94 * 64; idx += 1024) {
    int cc = idx >> 6;
    sdiag[idx] = maskT[(size_t)cc * SEL_PAD + cc * 64 + (idx & 63)];
  }
  __syncthreads();

  for (int c = 0; c < 94; c++) {
    size_t colbase = (size_t)c * SEL_PAD;
    int i0 = 2 * tid;
    ulonglong2 v0 = *(const ulonglong2*)&maskT[colbase + i0];
    ulonglong2 v1 = *(const ulonglong2*)&maskT[colbase + i0 + 2048];
    ulonglong2 v2 = *(const ulonglong2*)&maskT[colbase + i0 + 4096];
    u64 k0 = skept[i0 >> 6];
    u64 k1 = skept[(i0 + 2048) >> 6];
    u64 k2 = skept[(i0 + 4096) >> 6];
    int sh = i0 & 63;
    u64 acc = 0;
    if ((k0 >> sh) & 1) acc |= v0.x;
    if ((k0 >> (sh + 1)) & 1) acc |= v0.y;
    if ((k1 >> sh) & 1) acc |= v1.x;
    if ((k1 >> (sh + 1)) & 1) acc |= v1.y;
    if ((k2 >> sh) & 1) acc |= v2.x;
    if ((k2 >> (sh + 1)) & 1) acc |= v2.y;
    u32 lo = (u32)acc, hi = (u32)(acc >> 32);
#pragma unroll
    for (int off = 1; off < 64; off <<= 1) {
      lo |= (u32)__shfl_xor((int)lo, off, 64);
      hi |= (u32)__shfl_xor((int)hi, off, 64);
    }
    if (lane == 0) wacc[wv] = ((u64)hi << 32) | (u64)lo;
    __syncthreads();
    if (wv == 0) {
      u64 a = wacc[lane & 15];
      u32 alo = (u32)a, ahi = (u32)(a >> 32);
#pragma unroll
      for (int off = 1; off < 16; off <<= 1) {
        alo |= (u32)__shfl_xor((int)alo, off, 64);
        ahi |= (u32)__shfl_xor((int)ahi, off, 64);
      }
      u64 supp = ((u64)ahi << 32) | (u64)alo;
      u64 cur = svalid[c] & ~supp;
      u64 d = sdiag[c * 64 + lane];
      u64 rem = cur, kept = 0;
      while (rem) {
        int b = __builtin_ctzll(rem);
        kept |= (1ull << b);
        u64 dead = shfl64(d, b);
        rem &= ~dead;
        rem &= ~(1ull << b);
      }
      if (lane == 0) skept[c] = kept;
    }
    __syncthreads();
  }

  // ---- finalize phase (uses skept in LDS; identical outputs to final_k) ----
  if (tid == 0) {
    u32 s = 0;
    for (int w = 0; w < 94; w++) { pre[w] = s; s += (u32)__popcll(skept[w]); }
    pre[94] = s;
  }
  __syncthreads();
  u32 total = pre[94];
  for (int p = tid; p < K_SEL; p += 1024) {
    int w = p >> 6, b = p & 63;
    u64 word = skept[w];
    u32 kb = pre[w] + (u32)__popcll(word & ((1ull << b) - 1ull));
    bool kept = (word >> b) & 1ull;
    int slot = -1; float sc = -1.f;
    if (kept) {
      if (kb < 300) { slot = (int)kb; sc = ssc[p]; }
    } else {
      u32 s2 = total + (u32)p - kb;
      if (s2 < 300) slot = (int)s2;
    }
    if (slot >= 0) {
      out[slot * 5 + 0] = sx1[p];
      out[slot * 5 + 1] = sy1[p];
      out[slot * 5 + 2] = sx2[p];
      out[slot * 5 + 3] = sy2[p];
      out[slot * 5 + 4] = sc;
    }
  }
}

extern "C" void kernel_launch(void* const* d_in, const int* in_sizes, int n_in,
                              void* d_out, int out_size, void* d_ws, size_t ws_size,
                              hipStream_t stream) {
  const float* feat   = (const float*)d_in[0];
  const float* conv_w = (const float*)d_in[2];
  const float* conv_b = (const float*)d_in[3];
  const float* cls_w  = (const float*)d_in[4];
  const float* cls_b  = (const float*)d_in[5];
  const float* bbox_w = (const float*)d_in[6];
  const float* bbox_b = (const float*)d_in[7];
  float* out = (float*)d_out;
  char* ws = (char*)d_ws;

  float*  rpn    = (float*)(ws + OFF_RPN);
  float4* boxes  = (float4*)(ws + OFF_BOXES);
  float*  scores = (float*)(ws + OFF_SCORES);
  u64*    keys   = (u64*)(ws + OFF_KEYS);
  SelState* st   = (SelState*)(ws + OFF_STATE);
  u64*    selk   = (u64*)(ws + OFF_SELK);
  float*  sx1    = (float*)(ws + OFF_SX1);
  float*  sy1    = (float*)(ws + OFF_SY1);
  float*  sx2    = (float*)(ws + OFF_SX2);
  float*  sy2    = (float*)(ws + OFF_SY2);
  float*  ssc    = (float*)(ws + OFF_SSC);
  u64*    maskT  = (u64*)(ws + OFF_MASKT);
  float*  wT     = (float*)(ws + OFF_WT);
  u32*    hist   = (u32*)(ws + OFF_HIST);

  wtrz_k<<<184, 256, 0, stream>>>(conv_w, wT, hist, st);
  conv_k<<<800, 256, 0, stream>>>(feat, wT, conv_b, rpn);
  heads_k<<<800, 256, 0, stream>>>(rpn, cls_w, cls_b, bbox_w, bbox_b, boxes, scores, keys);

  hist_k<<<900, 256, 0, stream>>>(keys, st, hist,         13,  0);
  scan_k<<<1, 1024, 0, stream>>>(hist,         st, 13);
  hist_k<<<900, 256, 0, stream>>>(keys, st, hist +  8192, 13, 13);
  scan_k<<<1, 1024, 0, stream>>>(hist +  8192, st, 13);
  hist_k<<<900, 256, 0, stream>>>(keys, st, hist + 16384, 13, 26);
  scan_k<<<1, 1024, 0, stream>>>(hist + 16384, st, 13);
  hist_k<<<900, 256, 0, stream>>>(keys, st, hist + 24576, 13, 39);
  scan_k<<<1, 1024, 0, stream>>>(hist + 24576, st, 13);
  hist_k<<<900, 256, 0, stream>>>(keys, st, hist + 32768, 12, 52);
  scan_k<<<1, 1024, 0, stream>>>(hist + 32768, st, 12);

  compact_k<<<900, 256, 0, stream>>>(keys, st, selk);
  rank_k<<<94, 64, 0, stream>>>(selk, boxes, scores, sx1, sy1, sx2, sy2, ssc);
  mask_k<<<188, 256, 0, stream>>>(sx1, sy1, sx2, sy2, maskT);
  nmsf_k<<<1, 1024, 0, stream>>>(maskT, sx1, sy1, sx2, sy2, ssc, out);
}